// Round 7
// baseline (34.539 us; speedup 1.0000x reference)
//
#include <hip/hip_runtime.h>
#include <math.h>

// Problem constants
constexpr int NT = 32;     // components
constexpr int ND = 1024;   // dim
constexpr int NB = 4096;   // batch

// Workspace layout (float offsets)
//  ivc : [256][32][4] chunk-major inv_var            @ 0       (32768 floats)
//  m2c : [256][32][4] chunk-major (-2*mu*inv_var)    @ 32768   (32768)
//  c2  : [32]  sum(mu^2*inv_var)                     @ 65536
//  Ng  : [32]  sum_b kl_gaussian                     @ 65568
//  Npi : [32]  sum_b log_pi                          @ 65600
//  klg : [B][T]                                      @ 65664   (131072)
//  lpi : [B][T]                                      @ 196736  (131072)
constexpr int OFF_M2C = 32768;
constexpr int OFF_C2  = 65536;
constexpr int OFF_NG  = 65568;
constexpr int OFF_NPI = 65600;
constexpr int OFF_KLG = 65664;
constexpr int OFF_LPI = 196736;

// ---------------------------------------------------------------------------
// Kernel A: per-component stats + zeroing of accumulators.
// grid = 32 (one block per component t), block = 256 (one chunk of 4 d's each)
// ---------------------------------------------------------------------------
__global__ __launch_bounds__(256) void k_stats(const float* __restrict__ mu,
                                               const float* __restrict__ rho,
                                               float* __restrict__ ws,
                                               float* __restrict__ out) {
  float* ivc = ws;
  float* m2c = ws + OFF_M2C;
  float* c2  = ws + OFF_C2;
  float* Ng  = ws + OFF_NG;
  float* Npi = ws + OFF_NPI;

  const int t = blockIdx.x;
  const int c = threadIdx.x;  // chunk index 0..255 (covers d = 4c..4c+3)

  float4 mu4  = reinterpret_cast<const float4*>(mu  + t * ND)[c];
  float4 rho4 = reinterpret_cast<const float4*>(rho + t * ND)[c];

  float rr[4] = {rho4.x, rho4.y, rho4.z, rho4.w};
  float mm[4] = {mu4.x,  mu4.y,  mu4.z,  mu4.w};
  float iv[4], m2[4];
  float c2p = 0.0f;
#pragma unroll
  for (int j = 0; j < 4; ++j) {
    float sd  = log1pf(expf(rr[j]));   // softplus
    float ivv = 1.0f / (sd * sd);
    iv[j] = ivv;
    m2[j] = -2.0f * mm[j] * ivv;
    c2p  += mm[j] * mm[j] * ivv;
  }
  float4 iv4 = {iv[0], iv[1], iv[2], iv[3]};
  float4 m24 = {m2[0], m2[1], m2[2], m2[3]};
  reinterpret_cast<float4*>(ivc)[c * NT + t] = iv4;   // chunk-major
  reinterpret_cast<float4*>(m2c)[c * NT + t] = m24;

  // block reduction of c2p (4 waves)
#pragma unroll
  for (int m = 32; m >= 1; m >>= 1) c2p += __shfl_xor(c2p, m, 64);
  __shared__ float red[4];
  const int wave = threadIdx.x >> 6, lane = threadIdx.x & 63;
  if (lane == 0) red[wave] = c2p;
  __syncthreads();
  if (threadIdx.x == 0) {
    c2[t]  = red[0] + red[1] + red[2] + red[3];
    Ng[t]  = 0.0f;
    Npi[t] = 0.0f;
    if (t == 0) out[0] = 0.0f;   // must re-zero every launch (graph replays)
  }
}

// ---------------------------------------------------------------------------
// Kernel B v5: LDS-staged quad GEMM with K=2 t-blocking.
// grid = 512 blocks x 512 threads (8 waves). Block owns 8 rows of x.
//
// Wave q covers d-eighth (32 float4 chunks). Lane = (g, t16):
//   t16 = lane&15 owns components {t16, t16+16};
//   g = lane>>4 covers chunks [q*32+g*8, q*32+g*8+8).
// Each broadcast ds_read_b128 of x now feeds 16 FMAs (2 components) ->
// per-CU LDS instruction count halves vs round 6 (the modeled binding
// resource: LDS pipe is shared across the CU's 4 SIMDs). Each LDS instr
// also delivers 4 distinct float4s (one per g-group) instead of 2.
// iv/m2 VMEM bytes/instrs unchanged (coalesced 4x256B per instr, L2-hot).
// ---------------------------------------------------------------------------
__global__ __launch_bounds__(512, 4) void k_main(const float* __restrict__ x,
                                                 const float* __restrict__ beta,
                                                 float* __restrict__ ws) {
  const float* ivc = ws;
  const float* m2c = ws + OFF_M2C;
  const float* c2  = ws + OFF_C2;
  float* Ng  = ws + OFF_NG;
  float* Npi = ws + OFF_NPI;
  float* klg = ws + OFF_KLG;
  float* lpi = ws + OFF_LPI;

  const int tid  = threadIdx.x;
  const int q    = tid >> 6;        // wave = d-eighth (0..7)
  const int lane = tid & 63;
  const int g    = lane >> 4;       // chunk subgroup (0..3)
  const int t16  = lane & 15;       // component pair base
  const int row0 = blockIdx.x * 8;

  __shared__ float xs[8 * 1024];    // 32 KB: block's x slab, [row][d]
  __shared__ float part[8][8][32];  // [eighth][row][t] = 8 KB

  // ---- Stage x (coalesced, block-wide) ----
  {
    const float4* xg4 = reinterpret_cast<const float4*>(x) + (size_t)row0 * 256;
    float4* xs4w = reinterpret_cast<float4*>(xs);
#pragma unroll
    for (int k = 0; k < 4; ++k) {
      xs4w[k * 512 + tid] = xg4[k * 512 + tid];
    }
  }
  __syncthreads();

  // ---- FMA loop: x from LDS (broadcast), iv/m2 from L2 ----
  // lane's chunk base: cg = q*32 + g*8 (8 chunks = 32 d's)
  const int cg = q * 32 + g * 8;
  const float4* ivp = reinterpret_cast<const float4*>(ivc) + (size_t)cg * NT + t16;
  const float4* m2p = reinterpret_cast<const float4*>(m2c) + (size_t)cg * NT + t16;
  const float4* xs4 = reinterpret_cast<const float4*>(xs) + cg;

  float a0[8] = {0.f, 0.f, 0.f, 0.f, 0.f, 0.f, 0.f, 0.f};  // component t16
  float a1[8] = {0.f, 0.f, 0.f, 0.f, 0.f, 0.f, 0.f, 0.f};  // component t16+16
#pragma unroll 2
  for (int i = 0; i < 8; ++i) {
    float4 ivA = ivp[(size_t)i * NT];        // iv[t16]
    float4 ivB = ivp[(size_t)i * NT + 16];   // iv[t16+16]
    float4 mA  = m2p[(size_t)i * NT];
    float4 mB  = m2p[(size_t)i * NT + 16];
#pragma unroll
    for (int r = 0; r < 8; ++r) {
      float4 xv = xs4[r * 256 + i];   // one broadcast ds_read_b128, 16 FMAs
      a0[r] = fmaf(xv.x, fmaf(xv.x, ivA.x, mA.x), a0[r]);
      a0[r] = fmaf(xv.y, fmaf(xv.y, ivA.y, mA.y), a0[r]);
      a0[r] = fmaf(xv.z, fmaf(xv.z, ivA.z, mA.z), a0[r]);
      a0[r] = fmaf(xv.w, fmaf(xv.w, ivA.w, mA.w), a0[r]);
      a1[r] = fmaf(xv.x, fmaf(xv.x, ivB.x, mB.x), a1[r]);
      a1[r] = fmaf(xv.y, fmaf(xv.y, ivB.y, mB.y), a1[r]);
      a1[r] = fmaf(xv.z, fmaf(xv.z, ivB.z, mB.z), a1[r]);
      a1[r] = fmaf(xv.w, fmaf(xv.w, ivB.w, mB.w), a1[r]);
    }
  }
  // reduce over g (lane bits 4,5): all lanes end with full d-eighth sums
#pragma unroll
  for (int r = 0; r < 8; ++r) {
    a0[r] += __shfl_xor(a0[r], 16, 64);
    a0[r] += __shfl_xor(a0[r], 32, 64);
    a1[r] += __shfl_xor(a1[r], 16, 64);
    a1[r] += __shfl_xor(a1[r], 32, 64);
  }

  if (g == 0) {
#pragma unroll
    for (int r = 0; r < 8; ++r) part[q][r][t16] = a0[r];
  } else if (g == 1) {
#pragma unroll
    for (int r = 0; r < 8; ++r) part[q][r][t16 + 16] = a1[r];
  }
  __syncthreads();

  // epilogue on first 4 waves: rr = row-in-block (0..7), t2 = component
  const int rr = tid >> 5, t2 = tid & 31;
  float kv = 0.f, lp = 0.f;
  if (tid < 256) {
    float quad = 0.f;
#pragma unroll
    for (int qq = 0; qq < 8; ++qq) quad += part[qq][rr][t2];
    // kl_gaussian = log_pdfs + entropy = D/2 - 0.5*quad (log_std_sum cancels)
    kv = 512.0f - 0.5f * (quad + c2[t2]);
    klg[(size_t)(row0 + rr) * NT + t2] = kv;

    // log_pi: exclusive prefix scan of log1p(-beta) within each 32-lane group
    const float b = beta[(size_t)(row0 + rr) * NT + t2];
    const float l1m = log1pf(-b);
    float s = l1m;
#pragma unroll
    for (int d = 1; d < 32; d <<= 1) {
      float v = __shfl_up(s, (unsigned)d, 32);
      if (t2 >= d) s += v;
    }
    lp = logf(b) + (s - l1m);   // exclusive prefix + log(beta)
    lpi[(size_t)(row0 + rr) * NT + t2] = lp;
  }
  __syncthreads();                 // all part reads done before reuse
  if (tid < 256) {
    part[0][rr][t2] = kv;
    part[1][rr][t2] = lp;
  }
  __syncthreads();
  if (tid < 32) {
    float sg = 0.f, sp = 0.f;
#pragma unroll
    for (int r = 0; r < 8; ++r) { sg += part[0][r][tid]; sp += part[1][r][tid]; }
    atomicAdd(&Ng[tid],  sg);
    atomicAdd(&Npi[tid], sp);
  }
}

// ---------------------------------------------------------------------------
// Kernel D: mix, softmax over T, final weighted mean.
// grid = 512, block = 256 (4 waves, 2 rows per wave: one per 32-lane half)
// ---------------------------------------------------------------------------
__global__ __launch_bounds__(256) void k_final(const float* __restrict__ ws,
                                               float* __restrict__ out) {
  const float* Ng  = ws + OFF_NG;
  const float* Npi = ws + OFF_NPI;
  const float* klg = ws + OFF_KLG;
  const float* lpi = ws + OFF_LPI;

  const int tid  = threadIdx.x;
  const int wave = tid >> 6, lane = tid & 63;
  const int h = lane >> 5, t = lane & 31;
  const int row = blockIdx.x * 8 + wave * 2 + h;

  const float kg = klg[(size_t)row * NT + t];
  const float lp = lpi[(size_t)row * NT + t];
  const float ng = Ng[t], np = Npi[t];
  const float mix  = np / (ng + np);
  const float klgm = mix * kg;
  const float kl   = klgm + (1.0f - mix) * lp;

  // softmax over the 32 t-lanes (masks < 32 stay within each half)
  float m = kl;
#pragma unroll
  for (int mk = 16; mk >= 1; mk >>= 1) m = fmaxf(m, __shfl_xor(m, mk, 64));
  const float e = expf(kl - m);
  float num = e * klgm, den = e;
#pragma unroll
  for (int mk = 16; mk >= 1; mk >>= 1) {
    num += __shfl_xor(num, mk, 64);
    den += __shfl_xor(den, mk, 64);
  }
  float s = num / den;           // per-row sum_t phi*klgm (replicated in group)
  s += __shfl_xor(s, 32, 64);    // 2 rows of this wave

  __shared__ float red[4];
  if (lane == 0) red[wave] = s;
  __syncthreads();
  if (tid == 0)
    atomicAdd(out, (red[0] + red[1] + red[2] + red[3]) * (1.0f / (float)NB));
}

// ---------------------------------------------------------------------------
extern "C" void kernel_launch(void* const* d_in, const int* in_sizes, int n_in,
                              void* d_out, int out_size, void* d_ws, size_t ws_size,
                              hipStream_t stream) {
  const float* x    = (const float*)d_in[0];
  const float* mu   = (const float*)d_in[1];
  const float* rho  = (const float*)d_in[2];
  const float* beta = (const float*)d_in[3];
  float* out = (float*)d_out;
  float* ws  = (float*)d_ws;

  hipLaunchKernelGGL(k_stats, dim3(32),  dim3(256), 0, stream, mu, rho, ws, out);
  hipLaunchKernelGGL(k_main,  dim3(512), dim3(512), 0, stream, x, beta, ws);
  hipLaunchKernelGGL(k_final, dim3(512), dim3(256), 0, stream, ws, out);
}

// Round 8
// 29.018 us; speedup vs baseline: 1.1903x; 1.1903x over previous
//
#include <hip/hip_runtime.h>
#include <math.h>

// Problem constants
constexpr int NT = 32;     // components
constexpr int ND = 1024;   // dim
constexpr int NB = 4096;   // batch
constexpr int NBLK_MAIN = 512;   // k_main grid

// Workspace layout (float offsets)
//  ivc : [256][32][4] chunk-major inv_var            @ 0       (32768 floats)
//  m2c : [256][32][4] chunk-major (-2*mu*inv_var)    @ 32768   (32768)
//  c2  : [32]  sum(mu^2*inv_var)                     @ 65536
//  klg : [B][T]                                      @ 65664   (131072)
//  lpi : [B][T]                                      @ 196736  (131072)
//  Pg  : [512][32] per-block partial sum klg         @ 327808  (16384)
//  Pp  : [512][32] per-block partial sum lpi         @ 344192  (16384)
constexpr int OFF_M2C = 32768;
constexpr int OFF_C2  = 65536;
constexpr int OFF_KLG = 65664;
constexpr int OFF_LPI = 196736;
constexpr int OFF_PG  = 327808;
constexpr int OFF_PP  = 344192;

// ---------------------------------------------------------------------------
// Kernel A: per-component stats + zero out[0].
// grid = 32 (one block per component t), block = 256 (one chunk of 4 d's each)
// ---------------------------------------------------------------------------
__global__ __launch_bounds__(256) void k_stats(const float* __restrict__ mu,
                                               const float* __restrict__ rho,
                                               float* __restrict__ ws,
                                               float* __restrict__ out) {
  float* ivc = ws;
  float* m2c = ws + OFF_M2C;
  float* c2  = ws + OFF_C2;

  const int t = blockIdx.x;
  const int c = threadIdx.x;  // chunk index 0..255 (covers d = 4c..4c+3)

  float4 mu4  = reinterpret_cast<const float4*>(mu  + t * ND)[c];
  float4 rho4 = reinterpret_cast<const float4*>(rho + t * ND)[c];

  float rr[4] = {rho4.x, rho4.y, rho4.z, rho4.w};
  float mm[4] = {mu4.x,  mu4.y,  mu4.z,  mu4.w};
  float iv[4], m2[4];
  float c2p = 0.0f;
#pragma unroll
  for (int j = 0; j < 4; ++j) {
    float sd  = log1pf(expf(rr[j]));   // softplus
    float ivv = 1.0f / (sd * sd);
    iv[j] = ivv;
    m2[j] = -2.0f * mm[j] * ivv;
    c2p  += mm[j] * mm[j] * ivv;
  }
  float4 iv4 = {iv[0], iv[1], iv[2], iv[3]};
  float4 m24 = {m2[0], m2[1], m2[2], m2[3]};
  reinterpret_cast<float4*>(ivc)[c * NT + t] = iv4;   // chunk-major
  reinterpret_cast<float4*>(m2c)[c * NT + t] = m24;

  // block reduction of c2p (4 waves)
#pragma unroll
  for (int m = 32; m >= 1; m >>= 1) c2p += __shfl_xor(c2p, m, 64);
  __shared__ float red[4];
  const int wave = threadIdx.x >> 6, lane = threadIdx.x & 63;
  if (lane == 0) red[wave] = c2p;
  __syncthreads();
  if (threadIdx.x == 0) {
    c2[t] = red[0] + red[1] + red[2] + red[3];
    if (t == 0) out[0] = 0.0f;   // must re-zero every launch (graph replays)
  }
}

// ---------------------------------------------------------------------------
// Kernel B v6: LDS-staged quad GEMM (round-6 inner loop) with NO global
// atomics: per-block Ng/Npi partials stored plain into Pg/Pp (the round 1-7
// atomicAdds into the same two 128-B lines were ~32768 serialized L2 atomic
// ops == the hidden ~20 us).
// grid = 512 blocks x 512 threads (8 waves). Block owns 8 rows of x.
// ---------------------------------------------------------------------------
__global__ __launch_bounds__(512, 4) void k_main(const float* __restrict__ x,
                                                 const float* __restrict__ beta,
                                                 float* __restrict__ ws) {
  const float* ivc = ws;
  const float* m2c = ws + OFF_M2C;
  const float* c2  = ws + OFF_C2;
  float* klg = ws + OFF_KLG;
  float* lpi = ws + OFF_LPI;
  float* Pg  = ws + OFF_PG;
  float* Pp  = ws + OFF_PP;

  const int tid  = threadIdx.x;
  const int q    = tid >> 6;        // wave = d-eighth (0..7)
  const int lane = tid & 63;
  const int h = lane >> 5, t = lane & 31;
  const int row0 = blockIdx.x * 8;

  __shared__ float xs[8 * 1024];    // 32 KB: block's x slab, [row][d]
  __shared__ float part[8][8][32];  // [eighth][row][t] = 8 KB

  // ---- Stage x (coalesced, block-wide) ----
  {
    const float4* xg4 = reinterpret_cast<const float4*>(x) + (size_t)row0 * 256;
    float4* xs4w = reinterpret_cast<float4*>(xs);
#pragma unroll
    for (int k = 0; k < 4; ++k) {
      xs4w[k * 512 + tid] = xg4[k * 512 + tid];
    }
  }
  __syncthreads();

  // ---- FMA loop: x from LDS (broadcast), iv/m2 from L2 ----
  // chunk c = q*32 + h*16 + i (i=0..15); float4 idx = c*32 + t (chunk-major)
  const int c0 = q * 32 + h * 16;
  const float4* ivp = reinterpret_cast<const float4*>(ivc) + (size_t)c0 * NT + t;
  const float4* m2p = reinterpret_cast<const float4*>(m2c) + (size_t)c0 * NT + t;
  const float4* xs4 = reinterpret_cast<const float4*>(xs) + c0;

  float a[8] = {0.f, 0.f, 0.f, 0.f, 0.f, 0.f, 0.f, 0.f};
#pragma unroll 4
  for (int i = 0; i < 16; ++i) {
    float4 iv4 = ivp[(size_t)i * NT];
    float4 m24 = m2p[(size_t)i * NT];
#pragma unroll
    for (int r = 0; r < 8; ++r) {
      float4 xv = xs4[r * 256 + i];   // broadcast ds_read_b128
      // acc += x*(x*iv + m2) == x^2*iv + x*m2
      a[r] = fmaf(xv.x, fmaf(xv.x, iv4.x, m24.x), a[r]);
      a[r] = fmaf(xv.y, fmaf(xv.y, iv4.y, m24.y), a[r]);
      a[r] = fmaf(xv.z, fmaf(xv.z, iv4.z, m24.z), a[r]);
      a[r] = fmaf(xv.w, fmaf(xv.w, iv4.w, m24.w), a[r]);
    }
  }
  // combine the two 64-d sub-halves within the wave
#pragma unroll
  for (int r = 0; r < 8; ++r) a[r] += __shfl_xor(a[r], 32, 64);

  if (h == 0) {
#pragma unroll
    for (int r = 0; r < 8; ++r) part[q][r][t] = a[r];
  }
  __syncthreads();

  // epilogue on first 4 waves: rr = row-in-block (0..7), t2 = component
  const int rr = tid >> 5, t2 = tid & 31;
  float kv = 0.f, lp = 0.f;
  if (tid < 256) {
    float quad = 0.f;
#pragma unroll
    for (int qq = 0; qq < 8; ++qq) quad += part[qq][rr][t2];
    // kl_gaussian = log_pdfs + entropy = D/2 - 0.5*quad (log_std_sum cancels)
    kv = 512.0f - 0.5f * (quad + c2[t2]);
    klg[(size_t)(row0 + rr) * NT + t2] = kv;

    // log_pi: exclusive prefix scan of log1p(-beta) within each 32-lane group
    const float b = beta[(size_t)(row0 + rr) * NT + t2];
    const float l1m = log1pf(-b);
    float s = l1m;
#pragma unroll
    for (int d = 1; d < 32; d <<= 1) {
      float v = __shfl_up(s, (unsigned)d, 32);
      if (t2 >= d) s += v;
    }
    lp = logf(b) + (s - l1m);   // exclusive prefix + log(beta)
    lpi[(size_t)(row0 + rr) * NT + t2] = lp;
  }
  __syncthreads();                 // all part reads done before reuse
  if (tid < 256) {
    part[0][rr][t2] = kv;
    part[1][rr][t2] = lp;
  }
  __syncthreads();
  if (tid < 32) {
    float sg = 0.f, sp = 0.f;
#pragma unroll
    for (int r = 0; r < 8; ++r) { sg += part[0][r][tid]; sp += part[1][r][tid]; }
    // plain coalesced stores -- no atomics
    Pg[(size_t)blockIdx.x * NT + tid] = sg;
    Pp[(size_t)blockIdx.x * NT + tid] = sp;
  }
}

// ---------------------------------------------------------------------------
// Kernel D v2: redundant per-block reduce of Pg/Pp (no atomics), then mix,
// softmax over T, weighted mean.
// grid = 256, block = 512 (8 waves; 16 rows/block, one per 32-lane group)
// ---------------------------------------------------------------------------
__global__ __launch_bounds__(512) void k_final(const float* __restrict__ ws,
                                               float* __restrict__ out) {
  const float* klg = ws + OFF_KLG;
  const float* lpi = ws + OFF_LPI;
  const float* Pg  = ws + OFF_PG;
  const float* Pp  = ws + OFF_PP;

  const int tid  = threadIdx.x;
  const int wave = tid >> 6, lane = tid & 63;
  const int t = tid & 31;        // component
  const int g = tid >> 5;        // reduce group 0..15 / row-in-block

  __shared__ float ngF[32], npF[32];
  __shared__ float redG[8][32], redP[8][32];
  __shared__ float red[8];

  // ---- Prologue: reduce the 512 per-block partials (redundant per block) --
  {
    float sg = 0.f, sp = 0.f;
#pragma unroll 8
    for (int b = g; b < NBLK_MAIN; b += 16) {
      sg += Pg[(size_t)b * NT + t];
      sp += Pp[(size_t)b * NT + t];
    }
    // combine the wave's two g-groups (lane ^ 32)
    sg += __shfl_xor(sg, 32, 64);
    sp += __shfl_xor(sp, 32, 64);
    if (lane < 32) { redG[wave][t] = sg; redP[wave][t] = sp; }
  }
  __syncthreads();
  if (tid < 32) {
    float ng = 0.f, np = 0.f;
#pragma unroll
    for (int w = 0; w < 8; ++w) { ng += redG[w][tid]; np += redP[w][tid]; }
    ngF[tid] = ng;
    npF[tid] = np;
  }
  __syncthreads();

  // ---- Phase C: mix + softmax over T + weighted mean ----
  const int row = blockIdx.x * 16 + g;
  const float kg = klg[(size_t)row * NT + t];
  const float lp = lpi[(size_t)row * NT + t];
  const float ng = ngF[t], np = npF[t];
  const float mix  = np / (ng + np);
  const float klgm = mix * kg;
  const float kl   = klgm + (1.0f - mix) * lp;

  // softmax over the 32 t-lanes (xor masks < 32 stay within each group)
  float m = kl;
#pragma unroll
  for (int mk = 16; mk >= 1; mk >>= 1) m = fmaxf(m, __shfl_xor(m, mk, 64));
  const float e = expf(kl - m);
  float num = e * klgm, den = e;
#pragma unroll
  for (int mk = 16; mk >= 1; mk >>= 1) {
    num += __shfl_xor(num, mk, 64);
    den += __shfl_xor(den, mk, 64);
  }
  float s = num / den;           // per-row sum_t phi*klgm (replicated in group)
  s += __shfl_xor(s, 32, 64);    // combine the wave's two rows

  if (lane == 0) red[wave] = s;
  __syncthreads();
  if (tid == 0) {
    float tot = 0.f;
#pragma unroll
    for (int w = 0; w < 8; ++w) tot += red[w];
    atomicAdd(out, tot * (1.0f / (float)NB));
  }
}

// ---------------------------------------------------------------------------
extern "C" void kernel_launch(void* const* d_in, const int* in_sizes, int n_in,
                              void* d_out, int out_size, void* d_ws, size_t ws_size,
                              hipStream_t stream) {
  const float* x    = (const float*)d_in[0];
  const float* mu   = (const float*)d_in[1];
  const float* rho  = (const float*)d_in[2];
  const float* beta = (const float*)d_in[3];
  float* out = (float*)d_out;
  float* ws  = (float*)d_ws;

  hipLaunchKernelGGL(k_stats, dim3(32),        dim3(256), 0, stream, mu, rho, ws, out);
  hipLaunchKernelGGL(k_main,  dim3(NBLK_MAIN), dim3(512), 0, stream, x, beta, ws);
  hipLaunchKernelGGL(k_final, dim3(256),       dim3(512), 0, stream, ws, out);
}